// Round 4
// baseline (694.788 us; speedup 1.0000x reference)
//
#include <hip/hip_runtime.h>

// Problem constants
#define BB   16
#define CC   16
#define HH   256
#define WW   256
#define HID  128
#define OUTC 13

typedef short short8 __attribute__((ext_vector_type(8)));
typedef float floatx16 __attribute__((ext_vector_type(16)));

__device__ __forceinline__ unsigned short f2bf(float x) {
    unsigned int u = __float_as_uint(x);
    u += 0x7fffu + ((u >> 16) & 1u);          // round-to-nearest-even
    return (unsigned short)(u >> 16);
}

// ws layout: W1F frags [mt 0..3][tap 0..8][lane 0..63][8 bf16]  = 36864 B
//            W2F frags [s 0..7][lane 0..63][8 bf16]             =  8192 B at +36864
#define W2F_OFF   36864

// ================= prep kernel: bake bf16 weight fragments (validated) ======
__global__ __launch_bounds__(256) void gca_prep(
    const float* __restrict__ w1, const float* __restrict__ w2,
    unsigned char* __restrict__ ws)
{
    const int id = blockIdx.x * 256 + threadIdx.x;   // 2816 total
    const float SX[9] = {-1.f, 0.f, 1.f, -2.f, 0.f, 2.f, -1.f, 0.f, 1.f};
    const float SY[9] = {-1.f, -2.f, -1.f, 0.f, 0.f, 0.f, 1.f, 2.f, 1.f};

    if (id < 2304) {                                  // W1eff frags
        const int mtG  = id / 576;
        const int rem  = id % 576;
        const int tap  = rem / 64;
        const int lane = rem % 64;
        const int p  = lane & 31, hi = lane >> 5;
        const int hid = 32 * mtG + p;
        const float cen = (tap == 4) ? 1.f : 0.f;
        const float sxv = SX[tap], syv = SY[tap];
        const float* wr = w1 + hid * 48;
        unsigned int o[4];
        for (int k = 0; k < 4; ++k) {
            int c0 = 8 * hi + 2 * k;
            float v0 = wr[c0]     * cen + wr[16 + c0]     * sxv + wr[32 + c0]     * syv;
            float v1 = wr[c0 + 1] * cen + wr[16 + c0 + 1] * sxv + wr[32 + c0 + 1] * syv;
            o[k] = (unsigned int)f2bf(v0) | ((unsigned int)f2bf(v1) << 16);
        }
        *(uint4*)(ws + (size_t)id * 16) = make_uint4(o[0], o[1], o[2], o[3]);
    } else if (id < 2816) {                           // W2 (outc padded 13->32) frags
        const int id2 = id - 2304;
        const int s    = id2 / 64;
        const int lane = id2 % 64;
        const int outc = lane & 31, hi = lane >> 5;
        unsigned int o[4];
        for (int k = 0; k < 4; ++k) {
            int hid0 = 16 * s + 8 * hi + 2 * k;
            float v0 = (outc < OUTC) ? w2[outc * HID + hid0]     : 0.f;
            float v1 = (outc < OUTC) ? w2[outc * HID + hid0 + 1] : 0.f;
            o[k] = (unsigned int)f2bf(v0) | ((unsigned int)f2bf(v1) << 16);
        }
        *(uint4*)(ws + W2F_OFF + (size_t)id2 * 16) = make_uint4(o[0], o[1], o[2], o[3]);
    }
}

// ================= main kernel ==============================================
// Block = 512 thr = 8 waves; 16-row x 32-col output tile. Halo tile 18x34x16c
// bf16 (pixel stride 10 dw -> 2-way banks, free) + full W1F staged in LDS.
// Wave w owns rows 2w,2w+1 with ALL 128 hids. One barrier after staging.
// GEMM1 runs as 2 passes of 2 m-tiles each, GEMM2 steps interleaved after each
// pass, to keep live VGPR state under the 128-reg / 4-waves-per-SIMD cap.
#define TILE_DW 6120            // 18*34*10
#define W1L_DW  9216            // 36864 B
#define LDS_DW  (TILE_DW + W1L_DW)   // 61344 B < 64 KB

__global__ __launch_bounds__(512, 4) void gca_main(
    const float* __restrict__ in,
    const float* __restrict__ b1,
    const unsigned char* __restrict__ ws,
    float* __restrict__ out)
{
    __shared__ unsigned int lds[LDS_DW];

    const int tid  = threadIdx.x;
    const int wid  = tid >> 6;     // 0..7
    const int lane = tid & 63;
    const int p    = lane & 31;    // pixel / n-index
    const int hi   = lane >> 5;    // k-half selector

    const int bI = blockIdx.x >> 7;          // image (16)
    const int rm = blockIdx.x & 127;         // 16 y-tiles x 8 x-tiles
    const int y0 = (rm >> 3) << 4;           // 16-row span
    const int x0 = (rm & 7)  << 5;           // 32-px span

    // ---- stage W1F (global ws -> LDS), 2304 uint4 ----
    for (int i = tid; i < 2304; i += 512) {
        uint4 v = ((const uint4*)ws)[i];
        *(uint4*)&lds[TILE_DW + 4 * i] = v;
    }

    // ---- stage halo tile (rows y0-1..y0+16, cols x0-1..x0+32), fp32->bf16 ----
    {
        unsigned short* tus = (unsigned short*)lds;
        const float* inb = in + ((size_t)bI << 20);
        for (int i = tid; i < 16 * 18 * 34; i += 512) {
            int c   = i / 612;
            int rem = i % 612;
            int row = rem / 34;
            int col = rem % 34;
            int y = (y0 + row - 1) & 255;
            int x = (x0 + col - 1) & 255;
            float v = inb[(c << 16) + (y << 8) + x];
            tus[(row * 34 + col) * 20 + c] = f2bf(v);
        }
    }
    __syncthreads();

#pragma unroll 1
    for (int rr2 = 0; rr2 < 2; ++rr2) {
        const int r   = 2 * wid + rr2;       // local output row 0..15
        const int row = y0 + r;

        floatx16 acc2 = {};

#pragma unroll
        for (int pg = 0; pg < 2; ++pg) {     // hid halves: pg*64..pg*64+63
            // ---- acc init = b1 ----
            floatx16 acc1[2];
#pragma unroll
            for (int m = 0; m < 2; ++m)
#pragma unroll
                for (int q = 0; q < 4; ++q) {
                    float4 bv = *(const float4*)(b1 + 64 * pg + 32 * m + 8 * q + 4 * hi);
                    acc1[m][4 * q + 0] = bv.x;
                    acc1[m][4 * q + 1] = bv.y;
                    acc1[m][4 * q + 2] = bv.z;
                    acc1[m][4 * q + 3] = bv.w;
                }

            // ---- GEMM1 pass: 9 taps, 2 m-tiles, A from LDS ----
#pragma unroll
            for (int tap = 0; tap < 9; ++tap) {
                const int tr  = r + tap / 3;
                const int col = p + tap % 3;
                const int dwo = (tr * 34 + col) * 10 + 4 * hi;
                union { unsigned int u[4]; short8 s; } bfr;
                uint2 lo2 = *(const uint2*)&lds[dwo];
                uint2 hi2 = *(const uint2*)&lds[dwo + 2];
                bfr.u[0] = lo2.x; bfr.u[1] = lo2.y; bfr.u[2] = hi2.x; bfr.u[3] = hi2.y;
#pragma unroll
                for (int m = 0; m < 2; ++m) {
                    const int mt = 2 * pg + m;
                    short8 af = *(const short8*)&lds[TILE_DW + 4 * ((mt * 9 + tap) * 64 + lane)];
                    acc1[m] = __builtin_amdgcn_mfma_f32_32x32x16_bf16(af, bfr.s, acc1[m], 0, 0, 0);
                }
            }

            // ---- relu + pack: hrun[4m+q] holds hids 64pg+32m+8q+4hi+{0..3} ----
            uint2 hrun[8];
#pragma unroll
            for (int m = 0; m < 2; ++m)
#pragma unroll
                for (int q = 0; q < 4; ++q) {
                    float h0 = fmaxf(acc1[m][4 * q + 0], 0.f);
                    float h1 = fmaxf(acc1[m][4 * q + 1], 0.f);
                    float h2 = fmaxf(acc1[m][4 * q + 2], 0.f);
                    float h3 = fmaxf(acc1[m][4 * q + 3], 0.f);
                    hrun[4 * m + q].x = (unsigned int)f2bf(h0) | ((unsigned int)f2bf(h1) << 16);
                    hrun[4 * m + q].y = (unsigned int)f2bf(h2) | ((unsigned int)f2bf(h3) << 16);
                }

            // ---- GEMM2 steps s = 4pg..4pg+3 (K=16 each); B via half-swap ----
#pragma unroll
            for (int sp = 0; sp < 4; ++sp) {
                uint2 r0 = hrun[2 * sp];
                uint2 r1 = hrun[2 * sp + 1];
                uint2 x0s, x1s;
                x0s.x = (unsigned int)__shfl_xor((int)r0.x, 32);
                x0s.y = (unsigned int)__shfl_xor((int)r0.y, 32);
                x1s.x = (unsigned int)__shfl_xor((int)r1.x, 32);
                x1s.y = (unsigned int)__shfl_xor((int)r1.y, 32);
                union { unsigned int u[4]; short8 s8; } b2;
                uint2 lo = hi ? x1s : r0;     // k = 16s+8hi+{0..3}
                uint2 hg = hi ? r1  : x0s;    // k = 16s+8hi+{4..7}
                b2.u[0] = lo.x; b2.u[1] = lo.y; b2.u[2] = hg.x; b2.u[3] = hg.y;
                short8 a2 = *(const short8*)(ws + W2F_OFF + (size_t)((4 * pg + sp) * 64 + lane) * 16);
                acc2 = __builtin_amdgcn_mfma_f32_32x32x16_bf16(a2, b2.s8, acc2, 0, 0, 0);
            }
        }

        // ---- epilogue: residual add ch 3..15, passthrough ch 0..2 ----
#pragma unroll
        for (int reg = 0; reg < 16; ++reg) {
            int oc = (reg & 3) + 8 * (reg >> 2) + 4 * hi;
            if (oc < OUTC) {
                int idx = ((bI * 16 + 3 + oc) << 16) + (row << 8) + x0 + p;
                out[idx] = in[idx] + acc2[reg];
            }
        }
        {
            int c  = lane >> 5;          // ch 0,1 across the wave
            int idx = ((bI * 16 + c) << 16) + (row << 8) + x0 + p;
            out[idx] = in[idx];
            if (lane < 32) {
                int idx2 = ((bI * 16 + 2) << 16) + (row << 8) + x0 + lane;
                out[idx2] = in[idx2];
            }
        }
    }
}

extern "C" void kernel_launch(void* const* d_in, const int* in_sizes, int n_in,
                              void* d_out, int out_size, void* d_ws, size_t ws_size,
                              hipStream_t stream) {
    const float* x  = (const float*)d_in[0];
    const float* w1 = (const float*)d_in[1];
    const float* b1 = (const float*)d_in[2];
    const float* w2 = (const float*)d_in[3];
    float* out = (float*)d_out;
    unsigned char* ws = (unsigned char*)d_ws;

    hipLaunchKernelGGL(gca_prep, dim3(11), dim3(256), 0, stream, w1, w2, ws);
    hipLaunchKernelGGL(gca_main, dim3(2048), dim3(512), 0, stream, x, b1, ws, out);
}

// Round 5
// 545.333 us; speedup vs baseline: 1.2741x; 1.2741x over previous
//
#include <hip/hip_runtime.h>

// Problem constants
#define BB   16
#define CC   16
#define HH   256
#define WW   256
#define HID  128
#define OUTC 13

typedef short short8 __attribute__((ext_vector_type(8)));
typedef float floatx16 __attribute__((ext_vector_type(16)));

__device__ __forceinline__ unsigned short f2bf(float x) {
    unsigned int u = __float_as_uint(x);
    u += 0x7fffu + ((u >> 16) & 1u);          // round-to-nearest-even
    return (unsigned short)(u >> 16);
}

// ws layout: W1F frags [mt 0..3][tap 0..8][lane 0..63][8 bf16]  = 36864 B
//            W2F frags [s 0..7][lane 0..63][8 bf16]             =  8192 B at +36864
#define W2F_OFF   36864

// ================= prep kernel: bake bf16 weight fragments (validated) ======
__global__ __launch_bounds__(256) void gca_prep(
    const float* __restrict__ w1, const float* __restrict__ w2,
    unsigned char* __restrict__ ws)
{
    const int id = blockIdx.x * 256 + threadIdx.x;   // 2816 total
    const float SX[9] = {-1.f, 0.f, 1.f, -2.f, 0.f, 2.f, -1.f, 0.f, 1.f};
    const float SY[9] = {-1.f, -2.f, -1.f, 0.f, 0.f, 0.f, 1.f, 2.f, 1.f};

    if (id < 2304) {                                  // W1eff frags
        const int mtG  = id / 576;
        const int rem  = id % 576;
        const int tap  = rem / 64;
        const int lane = rem % 64;
        const int p  = lane & 31, hi = lane >> 5;
        const int hid = 32 * mtG + p;
        const float cen = (tap == 4) ? 1.f : 0.f;
        const float sxv = SX[tap], syv = SY[tap];
        const float* wr = w1 + hid * 48;
        unsigned int o[4];
        for (int k = 0; k < 4; ++k) {
            int c0 = 8 * hi + 2 * k;
            float v0 = wr[c0]     * cen + wr[16 + c0]     * sxv + wr[32 + c0]     * syv;
            float v1 = wr[c0 + 1] * cen + wr[16 + c0 + 1] * sxv + wr[32 + c0 + 1] * syv;
            o[k] = (unsigned int)f2bf(v0) | ((unsigned int)f2bf(v1) << 16);
        }
        *(uint4*)(ws + (size_t)id * 16) = make_uint4(o[0], o[1], o[2], o[3]);
    } else if (id < 2816) {                           // W2 (outc padded 13->32) frags
        const int id2 = id - 2304;
        const int s    = id2 / 64;
        const int lane = id2 % 64;
        const int outc = lane & 31, hi = lane >> 5;
        unsigned int o[4];
        for (int k = 0; k < 4; ++k) {
            int hid0 = 16 * s + 8 * hi + 2 * k;
            float v0 = (outc < OUTC) ? w2[outc * HID + hid0]     : 0.f;
            float v1 = (outc < OUTC) ? w2[outc * HID + hid0 + 1] : 0.f;
            o[k] = (unsigned int)f2bf(v0) | ((unsigned int)f2bf(v1) << 16);
        }
        *(uint4*)(ws + W2F_OFF + (size_t)id2 * 16) = make_uint4(o[0], o[1], o[2], o[3]);
    }
}

// ================= main kernel ==============================================
// Block = 256 thr = 4 waves; 8-row x 32-col output tile. LDS: halo tile
// 10x34x16c bf16 (pixel stride 10 dw) + full W1F (36.8 KB) = 50.4 KB
// -> 3 blocks/CU (151 of 160 KB). Wave w owns rows 2w,2w+1 with ALL 128 hids;
// one barrier after staging. pg-split keeps live VGPRs ~125 (cap 168 via
// __launch_bounds__(256,3) -> 3 waves/SIMD, matching the LDS-set occupancy).
#define TILE_DW 3400            // 10*34*10
#define W1L_DW  9216            // 36864 B
#define LDS_DW  (TILE_DW + W1L_DW)   // 50464 B

__global__ __launch_bounds__(256, 3) void gca_main(
    const float* __restrict__ in,
    const float* __restrict__ b1,
    const unsigned char* __restrict__ ws,
    float* __restrict__ out)
{
    __shared__ unsigned int lds[LDS_DW];

    const int tid  = threadIdx.x;
    const int wid  = tid >> 6;     // 0..3
    const int lane = tid & 63;
    const int p    = lane & 31;    // pixel / n-index
    const int hi   = lane >> 5;    // k-half selector

    const int bI = blockIdx.x >> 8;          // image (16)
    const int rm = blockIdx.x & 255;         // 32 y-tiles x 8 x-tiles
    const int y0 = (rm >> 3) << 3;           // 8-row span
    const int x0 = (rm & 7)  << 5;           // 32-px span

    // ---- stage W1F (global ws -> LDS), 2304 uint4, 9 per thread ----
    for (int i = tid; i < 2304; i += 256) {
        uint4 v = ((const uint4*)ws)[i];
        *(uint4*)&lds[TILE_DW + 4 * i] = v;
    }

    // ---- stage halo tile (rows y0-1..y0+8, cols x0-1..x0+32), fp32->bf16 ----
    {
        unsigned short* tus = (unsigned short*)lds;
        const float* inb = in + ((size_t)bI << 20);
        for (int i = tid; i < 16 * 10 * 34; i += 256) {
            int c   = i / 340;
            int rem = i % 340;
            int row = rem / 34;
            int col = rem % 34;
            int y = (y0 + row - 1) & 255;
            int x = (x0 + col - 1) & 255;
            float v = inb[(c << 16) + (y << 8) + x];
            tus[(row * 34 + col) * 20 + c] = f2bf(v);
        }
    }
    __syncthreads();

#pragma unroll 1
    for (int rr2 = 0; rr2 < 2; ++rr2) {
        const int r   = 2 * wid + rr2;       // local output row 0..7
        const int row = y0 + r;

        floatx16 acc2 = {};

#pragma unroll
        for (int pg = 0; pg < 2; ++pg) {     // hid halves: pg*64..pg*64+63
            // ---- acc init = b1 ----
            floatx16 acc1[2];
#pragma unroll
            for (int m = 0; m < 2; ++m)
#pragma unroll
                for (int q = 0; q < 4; ++q) {
                    float4 bv = *(const float4*)(b1 + 64 * pg + 32 * m + 8 * q + 4 * hi);
                    acc1[m][4 * q + 0] = bv.x;
                    acc1[m][4 * q + 1] = bv.y;
                    acc1[m][4 * q + 2] = bv.z;
                    acc1[m][4 * q + 3] = bv.w;
                }

            // ---- GEMM1 pass: 9 taps, 2 m-tiles, A from LDS ----
#pragma unroll
            for (int tap = 0; tap < 9; ++tap) {
                const int tr  = r + tap / 3;
                const int col = p + tap % 3;
                const int dwo = (tr * 34 + col) * 10 + 4 * hi;
                union { unsigned int u[4]; short8 s; } bfr;
                uint2 lo2 = *(const uint2*)&lds[dwo];
                uint2 hi2 = *(const uint2*)&lds[dwo + 2];
                bfr.u[0] = lo2.x; bfr.u[1] = lo2.y; bfr.u[2] = hi2.x; bfr.u[3] = hi2.y;
#pragma unroll
                for (int m = 0; m < 2; ++m) {
                    const int mt = 2 * pg + m;
                    short8 af = *(const short8*)&lds[TILE_DW + 4 * ((mt * 9 + tap) * 64 + lane)];
                    acc1[m] = __builtin_amdgcn_mfma_f32_32x32x16_bf16(af, bfr.s, acc1[m], 0, 0, 0);
                }
            }

            // ---- relu + pack: hrun[4m+q] holds hids 64pg+32m+8q+4hi+{0..3} ----
            uint2 hrun[8];
#pragma unroll
            for (int m = 0; m < 2; ++m)
#pragma unroll
                for (int q = 0; q < 4; ++q) {
                    float h0 = fmaxf(acc1[m][4 * q + 0], 0.f);
                    float h1 = fmaxf(acc1[m][4 * q + 1], 0.f);
                    float h2 = fmaxf(acc1[m][4 * q + 2], 0.f);
                    float h3 = fmaxf(acc1[m][4 * q + 3], 0.f);
                    hrun[4 * m + q].x = (unsigned int)f2bf(h0) | ((unsigned int)f2bf(h1) << 16);
                    hrun[4 * m + q].y = (unsigned int)f2bf(h2) | ((unsigned int)f2bf(h3) << 16);
                }

            // ---- GEMM2 steps s = 4pg..4pg+3 (K=16 each); B via half-swap ----
#pragma unroll
            for (int sp = 0; sp < 4; ++sp) {
                uint2 r0 = hrun[2 * sp];
                uint2 r1 = hrun[2 * sp + 1];
                uint2 x0s, x1s;
                x0s.x = (unsigned int)__shfl_xor((int)r0.x, 32);
                x0s.y = (unsigned int)__shfl_xor((int)r0.y, 32);
                x1s.x = (unsigned int)__shfl_xor((int)r1.x, 32);
                x1s.y = (unsigned int)__shfl_xor((int)r1.y, 32);
                union { unsigned int u[4]; short8 s8; } b2;
                uint2 lo = hi ? x1s : r0;     // k = 16s+8hi+{0..3}
                uint2 hg = hi ? r1  : x0s;    // k = 16s+8hi+{4..7}
                b2.u[0] = lo.x; b2.u[1] = lo.y; b2.u[2] = hg.x; b2.u[3] = hg.y;
                short8 a2 = *(const short8*)(ws + W2F_OFF + (size_t)((4 * pg + sp) * 64 + lane) * 16);
                acc2 = __builtin_amdgcn_mfma_f32_32x32x16_bf16(a2, b2.s8, acc2, 0, 0, 0);
            }
        }

        // ---- epilogue: residual add ch 3..15, passthrough ch 0..2 ----
#pragma unroll
        for (int reg = 0; reg < 16; ++reg) {
            int oc = (reg & 3) + 8 * (reg >> 2) + 4 * hi;
            if (oc < OUTC) {
                int idx = ((bI * 16 + 3 + oc) << 16) + (row << 8) + x0 + p;
                out[idx] = in[idx] + acc2[reg];
            }
        }
        {
            int c  = lane >> 5;          // ch 0,1 across the wave
            int idx = ((bI * 16 + c) << 16) + (row << 8) + x0 + p;
            out[idx] = in[idx];
            if (lane < 32) {
                int idx2 = ((bI * 16 + 2) << 16) + (row << 8) + x0 + lane;
                out[idx2] = in[idx2];
            }
        }
    }
}

extern "C" void kernel_launch(void* const* d_in, const int* in_sizes, int n_in,
                              void* d_out, int out_size, void* d_ws, size_t ws_size,
                              hipStream_t stream) {
    const float* x  = (const float*)d_in[0];
    const float* w1 = (const float*)d_in[1];
    const float* b1 = (const float*)d_in[2];
    const float* w2 = (const float*)d_in[3];
    float* out = (float*)d_out;
    unsigned char* ws = (unsigned char*)d_ws;

    hipLaunchKernelGGL(gca_prep, dim3(11), dim3(256), 0, stream, w1, w2, ws);
    hipLaunchKernelGGL(gca_main, dim3(4096), dim3(256), 0, stream, x, b1, ws, out);
}

// Round 6
// 226.929 us; speedup vs baseline: 3.0617x; 2.4031x over previous
//
#include <hip/hip_runtime.h>

// Problem constants
#define BB   16
#define CC   16
#define HH   256
#define WW   256
#define HID  128
#define OUTC 13

typedef short short8 __attribute__((ext_vector_type(8)));
typedef float floatx16 __attribute__((ext_vector_type(16)));

__device__ __forceinline__ unsigned short f2bf(float x) {
    unsigned int u = __float_as_uint(x);
    u += 0x7fffu + ((u >> 16) & 1u);          // round-to-nearest-even
    return (unsigned short)(u >> 16);
}

// ws layout: W1F frags [mt 0..3][tap 0..8][lane 0..63][8 bf16]  = 36864 B
//            W2F frags [s 0..7][lane 0..63][8 bf16]             =  8192 B at +36864
#define W2F_OFF   36864

// ================= prep kernel: bake bf16 weight fragments (validated) ======
__global__ __launch_bounds__(256) void gca_prep(
    const float* __restrict__ w1, const float* __restrict__ w2,
    unsigned char* __restrict__ ws)
{
    const int id = blockIdx.x * 256 + threadIdx.x;   // 2816 total
    const float SX[9] = {-1.f, 0.f, 1.f, -2.f, 0.f, 2.f, -1.f, 0.f, 1.f};
    const float SY[9] = {-1.f, -2.f, -1.f, 0.f, 0.f, 0.f, 1.f, 2.f, 1.f};

    if (id < 2304) {                                  // W1eff frags
        const int mtG  = id / 576;
        const int rem  = id % 576;
        const int tap  = rem / 64;
        const int lane = rem % 64;
        const int p  = lane & 31, hi = lane >> 5;
        const int hid = 32 * mtG + p;
        const float cen = (tap == 4) ? 1.f : 0.f;
        const float sxv = SX[tap], syv = SY[tap];
        const float* wr = w1 + hid * 48;
        unsigned int o[4];
        for (int k = 0; k < 4; ++k) {
            int c0 = 8 * hi + 2 * k;
            float v0 = wr[c0]     * cen + wr[16 + c0]     * sxv + wr[32 + c0]     * syv;
            float v1 = wr[c0 + 1] * cen + wr[16 + c0 + 1] * sxv + wr[32 + c0 + 1] * syv;
            o[k] = (unsigned int)f2bf(v0) | ((unsigned int)f2bf(v1) << 16);
        }
        *(uint4*)(ws + (size_t)id * 16) = make_uint4(o[0], o[1], o[2], o[3]);
    } else if (id < 2816) {                           // W2 (outc padded 13->32) frags
        const int id2 = id - 2304;
        const int s    = id2 / 64;
        const int lane = id2 % 64;
        const int outc = lane & 31, hi = lane >> 5;
        unsigned int o[4];
        for (int k = 0; k < 4; ++k) {
            int hid0 = 16 * s + 8 * hi + 2 * k;
            float v0 = (outc < OUTC) ? w2[outc * HID + hid0]     : 0.f;
            float v1 = (outc < OUTC) ? w2[outc * HID + hid0 + 1] : 0.f;
            o[k] = (unsigned int)f2bf(v0) | ((unsigned int)f2bf(v1) << 16);
        }
        *(uint4*)(ws + W2F_OFF + (size_t)id2 * 16) = make_uint4(o[0], o[1], o[2], o[3]);
    }
}

// ================= main kernel ==============================================
// Block = 256 thr = 4 waves; 8-row x 32-col output tile. LDS: halo tile
// 10x34x16c bf16 (pixel stride 10 dw) + full W1F (36.8 KB) = 50.4 KB
// -> 3 blocks/CU. Wave w owns rows 2w,2w+1 with ALL 128 hids; one barrier.
// NO min-waves launch bound: R4/R5 showed it caps the UNIFIED VGPR+AGPR file
// and forces catastrophic scratch spills (WRITE_SIZE 64MiB -> 827MB).
// bf16 conversion by truncation via v_perm_b32 (1 inst / 2 floats).
#define TILE_DW 3400            // 10*34*10
#define W1L_DW  9216            // 36864 B
#define LDS_DW  (TILE_DW + W1L_DW)   // 50464 B

__global__ __launch_bounds__(256) void gca_main(
    const float* __restrict__ in,
    const float* __restrict__ b1,
    const unsigned char* __restrict__ ws,
    float* __restrict__ out)
{
    __shared__ unsigned int lds[LDS_DW];

    const int tid  = threadIdx.x;
    const int wid  = tid >> 6;     // 0..3
    const int lane = tid & 63;
    const int p    = lane & 31;    // pixel / n-index
    const int hi   = lane >> 5;    // k-half selector

    const int bI = blockIdx.x >> 8;          // image (16)
    const int rm = blockIdx.x & 255;         // 32 y-tiles x 8 x-tiles
    const int y0 = (rm >> 3) << 3;           // 8-row span
    const int x0 = (rm & 7)  << 5;           // 32-px span

    // ---- stage W1F (global ws -> LDS), 2304 uint4, 9 per thread ----
    for (int i = tid; i < 2304; i += 256) {
        uint4 v = ((const uint4*)ws)[i];
        *(uint4*)&lds[TILE_DW + 4 * i] = v;
    }

    // ---- stage halo tile, one pixel (16 ch) per thread: fp32 -> bf16 trunc ----
    {
        const float* inb = in + ((size_t)bI << 20);
        for (int i = tid; i < 340; i += 256) {      // 10 rows x 34 cols
            int row = i / 34;
            int col = i % 34;
            int y = (y0 + row - 1) & 255;
            int x = (x0 + col - 1) & 255;
            const float* src = inb + (y << 8) + x;
            const int dbase = (row * 34 + col) * 10;
#pragma unroll
            for (int cp = 0; cp < 4; ++cp) {
                unsigned int u0 = __float_as_uint(src[(size_t)(4 * cp + 0) << 16]);
                unsigned int u1 = __float_as_uint(src[(size_t)(4 * cp + 1) << 16]);
                unsigned int u2 = __float_as_uint(src[(size_t)(4 * cp + 2) << 16]);
                unsigned int u3 = __float_as_uint(src[(size_t)(4 * cp + 3) << 16]);
                uint2 v;
                v.x = __builtin_amdgcn_perm(u1, u0, 0x07060302u);  // {hi16(u0),hi16(u1)}
                v.y = __builtin_amdgcn_perm(u3, u2, 0x07060302u);
                *(uint2*)&lds[dbase + 2 * cp] = v;
            }
        }
    }
    __syncthreads();

#pragma unroll 1
    for (int rr2 = 0; rr2 < 2; ++rr2) {
        const int r   = 2 * wid + rr2;       // local output row 0..7
        const int row = y0 + r;

        floatx16 acc2 = {};

#pragma unroll
        for (int pg = 0; pg < 2; ++pg) {     // hid halves: pg*64..pg*64+63
            // ---- acc init = b1 ----
            floatx16 acc1[2];
#pragma unroll
            for (int m = 0; m < 2; ++m)
#pragma unroll
                for (int q = 0; q < 4; ++q) {
                    float4 bv = *(const float4*)(b1 + 64 * pg + 32 * m + 8 * q + 4 * hi);
                    acc1[m][4 * q + 0] = bv.x;
                    acc1[m][4 * q + 1] = bv.y;
                    acc1[m][4 * q + 2] = bv.z;
                    acc1[m][4 * q + 3] = bv.w;
                }

            // ---- GEMM1 pass: 9 taps, 2 m-tiles, A from LDS ----
#pragma unroll
            for (int tap = 0; tap < 9; ++tap) {
                const int tr  = r + tap / 3;
                const int col = p + tap % 3;
                const int dwo = (tr * 34 + col) * 10 + 4 * hi;
                union { unsigned int u[4]; short8 s; } bfr;
                uint2 lo2 = *(const uint2*)&lds[dwo];
                uint2 hi2 = *(const uint2*)&lds[dwo + 2];
                bfr.u[0] = lo2.x; bfr.u[1] = lo2.y; bfr.u[2] = hi2.x; bfr.u[3] = hi2.y;
#pragma unroll
                for (int m = 0; m < 2; ++m) {
                    const int mt = 2 * pg + m;
                    short8 af = *(const short8*)&lds[TILE_DW + 4 * ((mt * 9 + tap) * 64 + lane)];
                    acc1[m] = __builtin_amdgcn_mfma_f32_32x32x16_bf16(af, bfr.s, acc1[m], 0, 0, 0);
                }
            }

            // ---- relu + trunc-pack via v_perm: hrun[4m+q] = hids ..+{0..3} ----
            uint2 hrun[8];
#pragma unroll
            for (int m = 0; m < 2; ++m)
#pragma unroll
                for (int q = 0; q < 4; ++q) {
                    unsigned int h0 = __float_as_uint(fmaxf(acc1[m][4 * q + 0], 0.f));
                    unsigned int h1 = __float_as_uint(fmaxf(acc1[m][4 * q + 1], 0.f));
                    unsigned int h2 = __float_as_uint(fmaxf(acc1[m][4 * q + 2], 0.f));
                    unsigned int h3 = __float_as_uint(fmaxf(acc1[m][4 * q + 3], 0.f));
                    hrun[4 * m + q].x = __builtin_amdgcn_perm(h1, h0, 0x07060302u);
                    hrun[4 * m + q].y = __builtin_amdgcn_perm(h3, h2, 0x07060302u);
                }

            // ---- GEMM2 steps s = 4pg..4pg+3 (K=16 each); B via half-swap ----
#pragma unroll
            for (int sp = 0; sp < 4; ++sp) {
                uint2 r0 = hrun[2 * sp];
                uint2 r1 = hrun[2 * sp + 1];
                uint2 x0s, x1s;
                x0s.x = (unsigned int)__shfl_xor((int)r0.x, 32);
                x0s.y = (unsigned int)__shfl_xor((int)r0.y, 32);
                x1s.x = (unsigned int)__shfl_xor((int)r1.x, 32);
                x1s.y = (unsigned int)__shfl_xor((int)r1.y, 32);
                union { unsigned int u[4]; short8 s8; } b2;
                uint2 lo = hi ? x1s : r0;     // k = 16s+8hi+{0..3}
                uint2 hg = hi ? r1  : x0s;    // k = 16s+8hi+{4..7}
                b2.u[0] = lo.x; b2.u[1] = lo.y; b2.u[2] = hg.x; b2.u[3] = hg.y;
                short8 a2 = *(const short8*)(ws + W2F_OFF + (size_t)((4 * pg + sp) * 64 + lane) * 16);
                acc2 = __builtin_amdgcn_mfma_f32_32x32x16_bf16(a2, b2.s8, acc2, 0, 0, 0);
            }
        }

        // ---- epilogue: residual add ch 3..15, passthrough ch 0..2 ----
#pragma unroll
        for (int reg = 0; reg < 16; ++reg) {
            int oc = (reg & 3) + 8 * (reg >> 2) + 4 * hi;
            if (oc < OUTC) {
                int idx = ((bI * 16 + 3 + oc) << 16) + (row << 8) + x0 + p;
                out[idx] = in[idx] + acc2[reg];
            }
        }
        {
            int c  = lane >> 5;          // ch 0,1 across the wave
            int idx = ((bI * 16 + c) << 16) + (row << 8) + x0 + p;
            out[idx] = in[idx];
            if (lane < 32) {
                int idx2 = ((bI * 16 + 2) << 16) + (row << 8) + x0 + lane;
                out[idx2] = in[idx2];
            }
        }
    }
}

extern "C" void kernel_launch(void* const* d_in, const int* in_sizes, int n_in,
                              void* d_out, int out_size, void* d_ws, size_t ws_size,
                              hipStream_t stream) {
    const float* x  = (const float*)d_in[0];
    const float* w1 = (const float*)d_in[1];
    const float* b1 = (const float*)d_in[2];
    const float* w2 = (const float*)d_in[3];
    float* out = (float*)d_out;
    unsigned char* ws = (unsigned char*)d_ws;

    hipLaunchKernelGGL(gca_prep, dim3(11), dim3(256), 0, stream, w1, w2, ws);
    hipLaunchKernelGGL(gca_main, dim3(4096), dim3(256), 0, stream, x, b1, ws, out);
}